// Round 3
// baseline (7575.005 us; speedup 1.0000x reference)
//
#include <hip/hip_runtime.h>
#include <stdint.h>
#include <stdio.h>

#define T_ 10
#define B_ 16
#define S_ 200
#define D_ 768
#define H_ 300
#define NC_ 4
#define M_ (S_ * B_)   /* 3200 rows per t */
#define K5_ (5 * D_)   /* 3840 */
#define N2_ 2400       /* 2 dirs * 4H */
#define G4_ 1200       /* 4H */
#define HXW_SLOT 4864  /* u32 words per parity slot: 16 b x 304 (300 u used) */
#define HLDS_STRIDE 344 /* 172 words: m*172 mod 32 -> 2-way (free) on ds_read_b128 */
#define NTILE 130       /* 13 x 10 grid of 256x256 GEMM tiles */

typedef unsigned short u16;
typedef unsigned int u32;
typedef __attribute__((ext_vector_type(8))) short short8;
typedef __attribute__((ext_vector_type(4))) float float4v;
typedef __attribute__((ext_vector_type(4))) unsigned int u32x4;

static __device__ __forceinline__ u16 f2bf(float x) {
  union { float f; u32 u; } v; v.f = x;
  u32 u = v.u;
  u32 r = (u + 0x7FFFu + ((u >> 16) & 1u)) >> 16;
  return (u16)r;
}

static __device__ __forceinline__ void async16(const void* g, void* l) {
  __builtin_amdgcn_global_load_lds((const __attribute__((address_space(1))) u32*)g,
                                   (__attribute__((address_space(3))) u32*)l, 16, 0, 0);
}

static __device__ __forceinline__ float sigmoid_f(float x) {
  return 1.f / (1.f + __expf(-x));
}
static __device__ __forceinline__ float tanh_f(float x) {
  float e = __expf(2.f * x);
  return 1.f - 2.f / (e + 1.f);   // safe at e=inf -> 1, e=0 -> -1
}

// ---------------------------------------------------------------------------
// K0a: build S0 = bf16(seq), SA = a .* seq, SB = b .* seq  (layout [t][s][b][768])
//      plus before-state SA0/SB0 (t=0 before-state weights on seq[0])
// ---------------------------------------------------------------------------
__global__ void k_prep_s(const float* __restrict__ seq,
                         const float* __restrict__ sp, const float* __restrict__ ep,
                         const float* __restrict__ cp,
                         const float* __restrict__ bsp, const float* __restrict__ bep,
                         const float* __restrict__ bcp,
                         const float* __restrict__ um, const float* __restrict__ nm,
                         const float* __restrict__ am,
                         u16* __restrict__ s0, u16* __restrict__ sa, u16* __restrict__ sb,
                         u16* __restrict__ sa0, u16* __restrict__ sb0) {
  int bid = blockIdx.x;
  int tid = threadIdx.x;  // 256
  if (bid < T_ * M_) {
    int t = bid / M_;
    int r = bid % M_;
    int s = r >> 4, b = r & 15;
    float c0 = cp[(t * B_ + b) * NC_ + 0];
    float c1 = cp[(t * B_ + b) * NC_ + 1];
    float c2 = cp[(t * B_ + b) * NC_ + 2];
    int mi = (b * T_ + t) * S_ + s;
    float w = am[mi] * c0 + um[mi] * c1 + nm[mi] * c2;
    float aw = sp[(t * B_ + b) * S_ + s] * w;
    float bw = ep[(t * B_ + b) * S_ + s] * w;
    const float* x = seq + ((size_t)(t * B_ + b) * S_ + s) * D_;
    size_t ob = (size_t)bid * D_;
    for (int d = tid; d < D_; d += 256) {
      float xv = x[d];
      s0[ob + d] = f2bf(xv);
      sa[ob + d] = f2bf(aw * xv);
      sb[ob + d] = f2bf(bw * xv);
    }
  } else {
    int r = bid - T_ * M_;
    int s = r >> 4, b = r & 15;
    float c0 = bcp[b * NC_ + 0], c1 = bcp[b * NC_ + 1], c2 = bcp[b * NC_ + 2];
    int mi = (b * T_ + 0) * S_ + s;
    float w = am[mi] * c0 + um[mi] * c1 + nm[mi] * c2;
    float aw = bsp[b * S_ + s] * w;
    float bw = bep[b * S_ + s] * w;
    const float* x = seq + ((size_t)b * S_ + s) * D_;
    size_t ob = (size_t)r * D_;
    for (int d = tid; d < D_; d += 256) {
      float xv = x[d];
      sa0[ob + d] = f2bf(aw * xv);
      sb0[ob + d] = f2bf(bw * xv);
    }
  }
}

// ---------------------------------------------------------------------------
// K0b: Wcat bf16 [2400][3840], Whh padded bf16 [2][1200][320], bias=bih+bhh,
//      d_out seeded with bcls, hxw (tagged h exchange buffer) zeroed
// ---------------------------------------------------------------------------
__global__ void k_prep_w(const float* __restrict__ wf, const float* __restrict__ wb,
                         const float* __restrict__ whf, const float* __restrict__ whb,
                         const float* __restrict__ bihf, const float* __restrict__ bhhf,
                         const float* __restrict__ bihb, const float* __restrict__ bhhb,
                         const float* __restrict__ bcls,
                         u16* __restrict__ wcat, u16* __restrict__ whh,
                         float* __restrict__ bias, float* __restrict__ outp,
                         u32* __restrict__ hxw) {
  int bid = blockIdx.x, tid = threadIdx.x;
  if (bid < N2_) {
    const float* src = bid < G4_ ? wf + (size_t)bid * K5_ : wb + (size_t)(bid - G4_) * K5_;
    u16* dst = wcat + (size_t)bid * K5_;
    for (int k = tid; k < K5_; k += 256) dst[k] = f2bf(src[k]);
  } else if (bid < N2_ + 2 * G4_) {
    int r = bid - N2_;
    int dir = r / G4_, n = r % G4_;
    const float* src = (dir ? whb : whf) + (size_t)n * H_;
    u16* dst = whh + (size_t)(dir * G4_ + n) * 320;
    for (int k = tid; k < 320; k += 256) dst[k] = (k < H_) ? f2bf(src[k]) : (u16)0;
  } else {
    for (int i = tid; i < 2 * G4_; i += 256) {
      int dir = i / G4_, n = i % G4_;
      bias[i] = dir ? (bihb[n] + bhhb[n]) : (bihf[n] + bhhf[n]);
    }
    for (int i = tid; i < T_ * B_ * NC_; i += 256) outp[i] = bcls[i & 3];
    for (int i = tid; i < 2 * 2 * HXW_SLOT; i += 256) hxw[i] = 0;  // tag 0 = invalid
  }
}

// ---------------------------------------------------------------------------
// K_MAIN: fused launch per t, XCD-aware role map (blockIdx%8 round-robins
// over the 8 XCDs; if that mapping ever changes, only SPEED is affected).
//   steady==1 (grid 176):
//     bid%8==0, bid/8<5  -> LSTM dir0 wg w=bid/8  (all 5 on XCD0)
//     bid%8==1, bid/8<5  -> LSTM dir1 wg w=bid/8  (all 5 on XCD1)
//     bid%8>=2           -> GEMM worker (XCDs 2..7 only; no L2 pollution of
//                           the exchange XCDs), tile = (bid/8)*6 + bid%8-2
//     else               -> exit
//   steady==0 (grid 130): pure GEMM prologue, tile = bid.
// GEMM(t+1) writes parity slot (t+1)&1 consumed by the NEXT launch's LSTM.
// ---------------------------------------------------------------------------
__global__ __launch_bounds__(1024) void k_main(
    const u16* __restrict__ s0, const u16* __restrict__ sa, const u16* __restrict__ sb,
    const u16* __restrict__ sa0, const u16* __restrict__ sb0,
    const u16* __restrict__ wcat, float* __restrict__ zbase,
    const u16* __restrict__ whh, const float* __restrict__ bias,
    const float* __restrict__ wcls, u32* __restrict__ hxw,
    float* __restrict__ outp, float* __restrict__ cst,
    int t_lstm, int t_gemm, int steady) {
  __shared__ __align__(16) char lds_raw[32768];

  int tid = threadIdx.x;
  int lane = tid & 63, wv = tid >> 6;
  int bid = (int)blockIdx.x;

  int dir = 0, w = 0, tile = -1;
  bool lstm_role = false;
  if (steady) {
    int grp = bid >> 3, sub = bid & 7;
    if (sub < 2) {
      if (grp < 5) { lstm_role = true; dir = sub; w = grp; }
      else return;                       // spare block on exchange XCD: exit
    } else {
      if (t_gemm < 0) return;
      tile = grp * 6 + (sub - 2);        // 0..131
      if (tile >= NTILE) return;
    }
  } else {
    tile = bid;                          // prologue: exactly NTILE blocks
  }

  if (!lstm_role) {
    // ---------------- GEMM path: one 256x256 tile ----------------
    int mt = tile % 13, nt = tile / 13;
    int m0 = mt * 256, n0 = nt * 256;
    u16* As = (u16*)lds_raw;             // [256][32]
    u16* Bs = (u16*)(lds_raw + 16384);   // [256][32]
    int wm = wv & 3, wn = wv >> 2;

    const u16* ap[5];
    ap[0] = s0 + (size_t)t_gemm * M_ * D_;
    ap[1] = sa + (size_t)t_gemm * M_ * D_;
    ap[2] = sb + (size_t)t_gemm * M_ * D_;
    ap[3] = t_gemm ? sa + (size_t)(t_gemm - 1) * M_ * D_ : sa0;
    ap[4] = t_gemm ? sb + (size_t)(t_gemm - 1) * M_ * D_ : sb0;
    float* z = zbase + (size_t)(t_gemm & 1) * M_ * N2_;

    float4v acc[4][4];
#pragma unroll
    for (int i = 0; i < 4; i++)
#pragma unroll
      for (int j = 0; j < 4; j++) acc[i][j] = (float4v){0.f, 0.f, 0.f, 0.f};

    int rowA = tid >> 2;   // 0..255
    int seg = tid & 3;
    int mr = m0 + rowA; if (mr > M_ - 1) mr = M_ - 1;
    int nr = n0 + rowA; if (nr > N2_ - 1) nr = N2_ - 1;

    for (int which = 0; which < 5; ++which) {
      const u16* ab = which == 0 ? ap[0] : which == 1 ? ap[1] : which == 2 ? ap[2]
                      : which == 3 ? ap[3] : ap[4];
      for (int kk = 0; kk < 24; ++kk) {
        int kof = kk * 32;
        async16(ab + (size_t)mr * D_ + kof + seg * 8, As + wv * 512);
        async16(wcat + (size_t)nr * K5_ + which * D_ + kof + seg * 8, Bs + wv * 512);
        __syncthreads();
        short8 af[4], bf[4];
#pragma unroll
        for (int i = 0; i < 4; i++) {
          af[i] = *(const short8*)&As[(wm * 64 + i * 16 + (lane & 15)) * 32 + (lane >> 4) * 8];
          bf[i] = *(const short8*)&Bs[(wn * 64 + i * 16 + (lane & 15)) * 32 + (lane >> 4) * 8];
        }
#pragma unroll
        for (int i = 0; i < 4; i++)
#pragma unroll
          for (int j = 0; j < 4; j++)
            acc[i][j] = __builtin_amdgcn_mfma_f32_16x16x32_bf16(af[i], bf[j], acc[i][j], 0, 0, 0);
        __syncthreads();
      }
    }
#pragma unroll
    for (int i = 0; i < 4; i++) {
      int m = m0 + wm * 64 + i * 16 + (lane >> 4) * 4;
#pragma unroll
      for (int j = 0; j < 4; j++) {
        int n = n0 + wn * 64 + j * 16 + (lane & 15);
        if (n < N2_) {
#pragma unroll
          for (int r = 0; r < 4; r++)
            if (m + r < M_) z[(size_t)(m + r) * N2_ + n] = acc[i][j][r];
        }
      }
    }
    return;
  }

  // ---------------- LSTM path ----------------
  u16* h_lds = (u16*)lds_raw;                              // [16][HLDS_STRIDE]
  float* smem = (float*)(lds_raw + 16 * HLDS_STRIDE * 2);  // 4160 floats

  int t = t_lstm;
  int wgid = dir * 5 + w;
  int gate = wv >> 2, q = wv & 3;
  const float* z = zbase + (size_t)(t & 1) * M_ * N2_;

  // persistent Whh B-fragments: wave covers cols n = gate*300 + w*64 + q*16 + (lane&15)
  short8 bfr[10];
  {
    int col = lane & 15;
    int u = w * 64 + q * 16 + col;
    int krow = (lane >> 4) * 8;
    if (u < H_) {
      const u16* base = whh + (size_t)(dir * G4_ + gate * H_ + u) * 320 + krow;
#pragma unroll
      for (int kk = 0; kk < 10; ++kk) bfr[kk] = *(const short8*)(base + kk * 32);
    } else {
#pragma unroll
      for (int kk = 0; kk < 10; ++kk) bfr[kk] = (short8){0, 0, 0, 0, 0, 0, 0, 0};
    }
  }

  // thread view for gate/classifier phase
  int b = tid >> 6;
  int u_loc = tid & 63;
  int u_glob = w * 64 + u_loc;
  bool active = u_glob < H_;
  float bias_r[4];
#pragma unroll
  for (int g = 0; g < 4; ++g)
    bias_r[g] = active ? bias[dir * G4_ + g * H_ + u_glob] : 0.f;

  float c_state = t > 0 ? cst[wgid * 1024 + tid] : 0.f;
  float clsacc[4] = {0.f, 0.f, 0.f, 0.f};

  for (int i = tid; i < 16 * HLDS_STRIDE; i += 1024) h_lds[i] = 0;
  __syncthreads();

  u32* hx_base = hxw + dir * 2 * HXW_SLOT;

  // poll set: thread reads dwordx4 at words [tid*4, tid*4+4) and
  // [4096+tid*4, ...). word layout i = b*304 + u; tagged (g+1)<<16 | bf16(h).
  // pend0: steady state (skip own slice). pendA: launch boundary (include own).
  u32 pend0 = 0, pendA = 0;
  int lofs[8];
#pragma unroll
  for (int k = 0; k < 8; ++k) {
    int i = (k < 4) ? (tid * 4 + k) : (4096 + tid * 4 + (k - 4));
    lofs[k] = 0;
    if (i < 16 * 304) {
      int bb = i / 304;
      int uu = i - bb * 304;
      if (uu < H_) {
        lofs[k] = bb * HLDS_STRIDE + uu;
        pendA |= 1u << k;
        if (!(uu >= w * 64 && uu < (w + 1) * 64)) pend0 |= 1u << k;
      }
    }
  }

  for (int s_mod = 0; s_mod < S_; ++s_mod) {
    int g = t * S_ + s_mod;
    int s_in = dir ? (S_ - 1 - s_mod) : s_mod;

    // prefetch (independent of sync): z input row + Wcls column
    float z_in[4] = {0.f, 0.f, 0.f, 0.f}, wc[4] = {0.f, 0.f, 0.f, 0.f};
    if (active) {
      const float* zr = z + (size_t)(s_in * B_ + b) * N2_ + dir * G4_;
      int ycol = s_in * 600 + dir * H_ + u_glob;
#pragma unroll
      for (int gg = 0; gg < 4; ++gg) z_in[gg] = zr[gg * H_ + u_glob];
#pragma unroll
      for (int n = 0; n < 4; ++n) wc[n] = wcls[(size_t)n * (S_ * 600) + ycol];
    }

    if (g > 0) {
      const u32* src = hx_base + (g & 1) * HXW_SLOT;
      const u32* aA = src + tid * 4;
      const u32* aB = src + 4096 + tid * 4;
      u32 pend = (s_mod == 0) ? pendA : pend0;
      int tries = 0;
      while (pend && tries < (1 << 20)) {
        u32x4 gA, gB;
        if ((tries & 3) == 3) {
          // guaranteed-progress round: device scope (bypasses local L2)
          asm volatile(
              "global_load_dwordx4 %0, %2, off sc1\n\t"
              "global_load_dwordx4 %1, %3, off sc1\n\t"
              "s_waitcnt vmcnt(0)"
              : "=&v"(gA), "=&v"(gB)
              : "v"(aA), "v"(aB)
              : "memory");
        } else {
          // fast round: SE scope — hits the XCD-local L2 the producers
          // write through (placement puts all 5 WGs of a dir on one XCD)
          asm volatile(
              "global_load_dwordx4 %0, %2, off sc0\n\t"
              "global_load_dwordx4 %1, %3, off sc0\n\t"
              "s_waitcnt vmcnt(0)"
              : "=&v"(gA), "=&v"(gB)
              : "v"(aA), "v"(aB)
              : "memory");
        }
        __builtin_amdgcn_sched_barrier(0);
        u32 wd[8] = {gA[0], gA[1], gA[2], gA[3], gB[0], gB[1], gB[2], gB[3]};
#pragma unroll
        for (int k = 0; k < 8; ++k)
          if ((pend & (1u << k)) && (wd[k] >> 16) >= (u32)g) {
            h_lds[lofs[k]] = (u16)(wd[k] & 0xffffu);
            pend &= ~(1u << k);
          }
        ++tries;
      }
      __syncthreads();
    }

    // recurrent GEMV tile via MFMA: D[b][u] = sum_k h[b,k] * Whh[n,k]
    {
      float4v acc = (float4v){0.f, 0.f, 0.f, 0.f};
      int m = lane & 15;
      int kbase = (lane >> 4) * 8;
      const u16* hl = h_lds + m * HLDS_STRIDE + kbase;
#pragma unroll
      for (int kk = 0; kk < 10; ++kk) {
        short8 af = *(const short8*)(hl + kk * 32);
        acc = __builtin_amdgcn_mfma_f32_16x16x32_bf16(af, bfr[kk], acc, 0, 0, 0);
      }
      int col = lane & 15;
      int rb = (lane >> 4) * 4;
#pragma unroll
      for (int r = 0; r < 4; r++)
        smem[(gate * 16 + rb + r) * 65 + q * 16 + col] = acc[r];
    }
    __syncthreads();

    if (active) {
      float zi = smem[(0 * 16 + b) * 65 + u_loc] + z_in[0] + bias_r[0];
      float zf = smem[(1 * 16 + b) * 65 + u_loc] + z_in[1] + bias_r[1];
      float zg = smem[(2 * 16 + b) * 65 + u_loc] + z_in[2] + bias_r[2];
      float zo = smem[(3 * 16 + b) * 65 + u_loc] + z_in[3] + bias_r[3];
      float ig = sigmoid_f(zi);
      float fg = sigmoid_f(zf);
      float gg = tanh_f(zg);
      float og = sigmoid_f(zo);
      c_state = fg * c_state + ig * gg;
      float hval = og * tanh_f(c_state);
      u16 hb = f2bf(hval);
      // publish ASAP: tagged word, relaxed, no fence; lane = u -> contiguous
      u32 wrd = ((u32)(g + 1) << 16) | (u32)hb;
      __hip_atomic_store(&hx_base[((g + 1) & 1) * HXW_SLOT + b * 304 + u_glob], wrd,
                         __ATOMIC_RELAXED, __HIP_MEMORY_SCOPE_AGENT);
      // own slice goes straight to LDS for the next step
      h_lds[b * HLDS_STRIDE + u_glob] = hb;
      float rv = hval > 0.f ? hval : 0.f;
#pragma unroll
      for (int n = 0; n < 4; ++n) clsacc[n] += rv * wc[n];
    }

    if (s_mod == S_ - 1) {
      __syncthreads();
#pragma unroll
      for (int n = 0; n < 4; ++n) smem[(b * 64 + u_loc) * 4 + n] = clsacc[n];
      __syncthreads();
      if (tid < B_ * NC_) {
        int bb = tid >> 2, n = tid & 3;
        float s = 0.f;
        for (int u = 0; u < 64; ++u) s += smem[(bb * 64 + u) * 4 + n];
        atomicAdd(&outp[(t * B_ + bb) * NC_ + n], s);
      }
    }
  }
  cst[wgid * 1024 + tid] = c_state;
}

// ---------------------------------------------------------------------------
extern "C" void kernel_launch(void* const* d_in, const int* in_sizes, int n_in,
                              void* d_out, int out_size, void* d_ws, size_t ws_size,
                              hipStream_t stream) {
  const float* seq = (const float*)d_in[1];
  const float* sp = (const float*)d_in[2];
  const float* ep = (const float*)d_in[3];
  const float* cp = (const float*)d_in[4];
  const float* bsp = (const float*)d_in[5];
  const float* bep = (const float*)d_in[6];
  const float* bcp = (const float*)d_in[7];
  const float* um = (const float*)d_in[8];
  const float* nm = (const float*)d_in[9];
  const float* am = (const float*)d_in[10];
  const float* wihf = (const float*)d_in[11];
  const float* whhf = (const float*)d_in[12];
  const float* bihf = (const float*)d_in[13];
  const float* bhhf = (const float*)d_in[14];
  const float* wihb = (const float*)d_in[15];
  const float* whhb = (const float*)d_in[16];
  const float* bihb = (const float*)d_in[17];
  const float* bhhb = (const float*)d_in[18];
  const float* wcls = (const float*)d_in[19];
  const float* bcls = (const float*)d_in[20];

  char* ws = (char*)d_ws;
  size_t off = 0;
  auto alloc = [&](size_t bytes) -> char* {
    char* p = ws + off;
    off += (bytes + 255) & ~(size_t)255;
    return p;
  };
  u16* S0 = (u16*)alloc((size_t)T_ * M_ * D_ * 2);
  u16* SA = (u16*)alloc((size_t)T_ * M_ * D_ * 2);
  u16* SB = (u16*)alloc((size_t)T_ * M_ * D_ * 2);
  u16* SA0 = (u16*)alloc((size_t)M_ * D_ * 2);
  u16* SB0 = (u16*)alloc((size_t)M_ * D_ * 2);
  u16* WCAT = (u16*)alloc((size_t)N2_ * K5_ * 2);
  u16* WHH = (u16*)alloc((size_t)2 * G4_ * 320 * 2);
  float* BIAS = (float*)alloc((size_t)2 * G4_ * 4);
  float* Z = (float*)alloc((size_t)2 * M_ * N2_ * 4);   // parity double-buffer
  u32* HXW = (u32*)alloc((size_t)2 * 2 * HXW_SLOT * 4); // tagged h, 2 dirs x 2 slots
  float* CST = (float*)alloc((size_t)10 * 1024 * 4);

  if (off > ws_size) {
    fprintf(stderr, "[kernel] ws too small: need %zu, have %zu\n", off, ws_size);
    return;
  }

  hipLaunchKernelGGL(k_prep_s, dim3(T_ * M_ + M_), dim3(256), 0, stream,
                     seq, sp, ep, cp, bsp, bep, bcp, um, nm, am, S0, SA, SB, SA0, SB0);
  hipLaunchKernelGGL(k_prep_w, dim3(N2_ + 2 * G4_ + 1), dim3(256), 0, stream,
                     wihf, wihb, whhf, whhb, bihf, bhhf, bihb, bhhb, bcls,
                     WCAT, WHH, BIAS, (float*)d_out, HXW);
  // prologue: t=0 GEMM alone (fills Z slot 0), full-machine spread
  hipLaunchKernelGGL(k_main, dim3(NTILE), dim3(1024), 0, stream,
                     S0, SA, SB, SA0, SB0, WCAT, Z, WHH, BIAS, wcls, HXW,
                     (float*)d_out, CST, 0, 0, 0);
  for (int t = 0; t < T_; ++t) {
    // LSTM(t) on XCD0/1 + GEMM(t+1) on XCDs 2..7 hidden underneath
    hipLaunchKernelGGL(k_main, dim3(176), dim3(1024), 0, stream,
                       S0, SA, SB, SA0, SB0, WCAT, Z, WHH, BIAS, wcls, HXW,
                       (float*)d_out, CST, t, (t < T_ - 1) ? t + 1 : -1, 1);
  }
}

// Round 5
// 6262.904 us; speedup vs baseline: 1.2095x; 1.2095x over previous
//
#include <hip/hip_runtime.h>
#include <stdint.h>
#include <stdio.h>

#define T_ 10
#define B_ 16
#define S_ 200
#define D_ 768
#define H_ 300
#define NC_ 4
#define M_ (S_ * B_)   /* 3200 rows per t */
#define K5_ (5 * D_)   /* 3840 */
#define N2_ 2400       /* 2 dirs * 4H */
#define G4_ 1200       /* 4H */
#define HXW_SLOT 4864  /* u32 words per parity slot: 16 b x 304 (300 u used) */
#define HLDS_STRIDE 344 /* 172 words: m*172 mod 32 -> 2-way (free) on ds_read_b128 */
#define NTILE 130       /* 13 x 10 grid of 256x256 GEMM tiles */

typedef unsigned short u16;
typedef unsigned int u32;
typedef __attribute__((ext_vector_type(8))) short short8;
typedef __attribute__((ext_vector_type(4))) float float4v;
typedef __attribute__((ext_vector_type(4))) unsigned int u32x4;

static __device__ __forceinline__ u16 f2bf(float x) {
  union { float f; u32 u; } v; v.f = x;
  u32 u = v.u;
  u32 r = (u + 0x7FFFu + ((u >> 16) & 1u)) >> 16;
  return (u16)r;
}

static __device__ __forceinline__ void async16(const void* g, void* l) {
  __builtin_amdgcn_global_load_lds((const __attribute__((address_space(1))) u32*)g,
                                   (__attribute__((address_space(3))) u32*)l, 16, 0, 0);
}

static __device__ __forceinline__ float sigmoid_f(float x) {
  return 1.f / (1.f + __expf(-x));
}
static __device__ __forceinline__ float tanh_f(float x) {
  float e = __expf(2.f * x);
  return 1.f - 2.f / (e + 1.f);   // safe at e=inf -> 1, e=0 -> -1
}

// ---------------------------------------------------------------------------
// K0a: build S0 = bf16(seq), SA = a .* seq, SB = b .* seq  (layout [t][s][b][768])
//      plus before-state SA0/SB0 (t=0 before-state weights on seq[0])
// ---------------------------------------------------------------------------
__global__ void k_prep_s(const float* __restrict__ seq,
                         const float* __restrict__ sp, const float* __restrict__ ep,
                         const float* __restrict__ cp,
                         const float* __restrict__ bsp, const float* __restrict__ bep,
                         const float* __restrict__ bcp,
                         const float* __restrict__ um, const float* __restrict__ nm,
                         const float* __restrict__ am,
                         u16* __restrict__ s0, u16* __restrict__ sa, u16* __restrict__ sb,
                         u16* __restrict__ sa0, u16* __restrict__ sb0) {
  int bid = blockIdx.x;
  int tid = threadIdx.x;  // 256
  if (bid < T_ * M_) {
    int t = bid / M_;
    int r = bid % M_;
    int s = r >> 4, b = r & 15;
    float c0 = cp[(t * B_ + b) * NC_ + 0];
    float c1 = cp[(t * B_ + b) * NC_ + 1];
    float c2 = cp[(t * B_ + b) * NC_ + 2];
    int mi = (b * T_ + t) * S_ + s;
    float w = am[mi] * c0 + um[mi] * c1 + nm[mi] * c2;
    float aw = sp[(t * B_ + b) * S_ + s] * w;
    float bw = ep[(t * B_ + b) * S_ + s] * w;
    const float* x = seq + ((size_t)(t * B_ + b) * S_ + s) * D_;
    size_t ob = (size_t)bid * D_;
    for (int d = tid; d < D_; d += 256) {
      float xv = x[d];
      s0[ob + d] = f2bf(xv);
      sa[ob + d] = f2bf(aw * xv);
      sb[ob + d] = f2bf(bw * xv);
    }
  } else {
    int r = bid - T_ * M_;
    int s = r >> 4, b = r & 15;
    float c0 = bcp[b * NC_ + 0], c1 = bcp[b * NC_ + 1], c2 = bcp[b * NC_ + 2];
    int mi = (b * T_ + 0) * S_ + s;
    float w = am[mi] * c0 + um[mi] * c1 + nm[mi] * c2;
    float aw = bsp[b * S_ + s] * w;
    float bw = bep[b * S_ + s] * w;
    const float* x = seq + ((size_t)b * S_ + s) * D_;
    size_t ob = (size_t)r * D_;
    for (int d = tid; d < D_; d += 256) {
      float xv = x[d];
      sa0[ob + d] = f2bf(aw * xv);
      sb0[ob + d] = f2bf(bw * xv);
    }
  }
}

// ---------------------------------------------------------------------------
// K0b: Wcat bf16 [2400][3840], Whh padded bf16 [2][1200][320], bias=bih+bhh,
//      d_out seeded with bcls, hxw (tagged h exchange buffer) zeroed
// ---------------------------------------------------------------------------
__global__ void k_prep_w(const float* __restrict__ wf, const float* __restrict__ wb,
                         const float* __restrict__ whf, const float* __restrict__ whb,
                         const float* __restrict__ bihf, const float* __restrict__ bhhf,
                         const float* __restrict__ bihb, const float* __restrict__ bhhb,
                         const float* __restrict__ bcls,
                         u16* __restrict__ wcat, u16* __restrict__ whh,
                         float* __restrict__ bias, float* __restrict__ outp,
                         u32* __restrict__ hxw) {
  int bid = blockIdx.x, tid = threadIdx.x;
  if (bid < N2_) {
    const float* src = bid < G4_ ? wf + (size_t)bid * K5_ : wb + (size_t)(bid - G4_) * K5_;
    u16* dst = wcat + (size_t)bid * K5_;
    for (int k = tid; k < K5_; k += 256) dst[k] = f2bf(src[k]);
  } else if (bid < N2_ + 2 * G4_) {
    int r = bid - N2_;
    int dir = r / G4_, n = r % G4_;
    const float* src = (dir ? whb : whf) + (size_t)n * H_;
    u16* dst = whh + (size_t)(dir * G4_ + n) * 320;
    for (int k = tid; k < 320; k += 256) dst[k] = (k < H_) ? f2bf(src[k]) : (u16)0;
  } else {
    for (int i = tid; i < 2 * G4_; i += 256) {
      int dir = i / G4_, n = i % G4_;
      bias[i] = dir ? (bihb[n] + bhhb[n]) : (bihf[n] + bhhf[n]);
    }
    for (int i = tid; i < T_ * B_ * NC_; i += 256) outp[i] = bcls[i & 3];
    for (int i = tid; i < 2 * 2 * HXW_SLOT; i += 256) hxw[i] = 0;  // tag 0 = invalid
  }
}

// ---------------------------------------------------------------------------
// K_MAIN: fused launch per t, XCD-aware role map (blockIdx%8 round-robins
// over the 8 XCDs; if that mapping ever changes, only SPEED is affected —
// all exchange traffic is agent-scope, placement-independent).
//   steady==1 (grid 176):
//     bid%8==0, bid/8<5  -> LSTM dir0 wg w=bid/8  (intended: all on XCD0)
//     bid%8==1, bid/8<5  -> LSTM dir1 wg w=bid/8  (intended: all on XCD1)
//     bid%8>=2           -> GEMM worker, tile = (bid/8)*6 + bid%8-2
//                           (keeps GEMM streaming off the exchange XCDs)
//   steady==0 (grid 130): pure GEMM prologue, tile = bid.
// GEMM(t+1) writes parity slot (t+1)&1 consumed by the NEXT launch's LSTM
// (dispatch-boundary release/acquire carries it, same as z/cst always has).
// ---------------------------------------------------------------------------
__global__ __launch_bounds__(1024) void k_main(
    const u16* __restrict__ s0, const u16* __restrict__ sa, const u16* __restrict__ sb,
    const u16* __restrict__ sa0, const u16* __restrict__ sb0,
    const u16* __restrict__ wcat, float* __restrict__ zbase,
    const u16* __restrict__ whh, const float* __restrict__ bias,
    const float* __restrict__ wcls, u32* __restrict__ hxw,
    float* __restrict__ outp, float* __restrict__ cst,
    int t_lstm, int t_gemm, int steady) {
  __shared__ __align__(16) char lds_raw[32768];

  int tid = threadIdx.x;
  int lane = tid & 63, wv = tid >> 6;
  int bid = (int)blockIdx.x;

  int dir = 0, w = 0, tile = -1;
  bool lstm_role = false;
  if (steady) {
    int grp = bid >> 3, sub = bid & 7;
    if (sub < 2) {
      if (grp < 5) { lstm_role = true; dir = sub; w = grp; }
      else return;                       // spare block on exchange XCD: exit
    } else {
      if (t_gemm < 0) return;
      tile = grp * 6 + (sub - 2);        // 0..131
      if (tile >= NTILE) return;
    }
  } else {
    tile = bid;                          // prologue: exactly NTILE blocks
  }

  if (!lstm_role) {
    // ---------------- GEMM path: one 256x256 tile ----------------
    int mt = tile % 13, nt = tile / 13;
    int m0 = mt * 256, n0 = nt * 256;
    u16* As = (u16*)lds_raw;             // [256][32]
    u16* Bs = (u16*)(lds_raw + 16384);   // [256][32]
    int wm = wv & 3, wn = wv >> 2;

    const u16* ap[5];
    ap[0] = s0 + (size_t)t_gemm * M_ * D_;
    ap[1] = sa + (size_t)t_gemm * M_ * D_;
    ap[2] = sb + (size_t)t_gemm * M_ * D_;
    ap[3] = t_gemm ? sa + (size_t)(t_gemm - 1) * M_ * D_ : sa0;
    ap[4] = t_gemm ? sb + (size_t)(t_gemm - 1) * M_ * D_ : sb0;
    float* z = zbase + (size_t)(t_gemm & 1) * M_ * N2_;

    float4v acc[4][4];
#pragma unroll
    for (int i = 0; i < 4; i++)
#pragma unroll
      for (int j = 0; j < 4; j++) acc[i][j] = (float4v){0.f, 0.f, 0.f, 0.f};

    int rowA = tid >> 2;   // 0..255
    int seg = tid & 3;
    int mr = m0 + rowA; if (mr > M_ - 1) mr = M_ - 1;
    int nr = n0 + rowA; if (nr > N2_ - 1) nr = N2_ - 1;

    for (int which = 0; which < 5; ++which) {
      const u16* ab = which == 0 ? ap[0] : which == 1 ? ap[1] : which == 2 ? ap[2]
                      : which == 3 ? ap[3] : ap[4];
      for (int kk = 0; kk < 24; ++kk) {
        int kof = kk * 32;
        async16(ab + (size_t)mr * D_ + kof + seg * 8, As + wv * 512);
        async16(wcat + (size_t)nr * K5_ + which * D_ + kof + seg * 8, Bs + wv * 512);
        __syncthreads();
        short8 af[4], bf[4];
#pragma unroll
        for (int i = 0; i < 4; i++) {
          af[i] = *(const short8*)&As[(wm * 64 + i * 16 + (lane & 15)) * 32 + (lane >> 4) * 8];
          bf[i] = *(const short8*)&Bs[(wn * 64 + i * 16 + (lane & 15)) * 32 + (lane >> 4) * 8];
        }
#pragma unroll
        for (int i = 0; i < 4; i++)
#pragma unroll
          for (int j = 0; j < 4; j++)
            acc[i][j] = __builtin_amdgcn_mfma_f32_16x16x32_bf16(af[i], bf[j], acc[i][j], 0, 0, 0);
        __syncthreads();
      }
    }
#pragma unroll
    for (int i = 0; i < 4; i++) {
      int m = m0 + wm * 64 + i * 16 + (lane >> 4) * 4;
#pragma unroll
      for (int j = 0; j < 4; j++) {
        int n = n0 + wn * 64 + j * 16 + (lane & 15);
        if (n < N2_) {
#pragma unroll
          for (int r = 0; r < 4; r++)
            if (m + r < M_) z[(size_t)(m + r) * N2_ + n] = acc[i][j][r];
        }
      }
    }
    return;
  }

  // ---------------- LSTM path ----------------
  u16* h_lds = (u16*)lds_raw;                              // [16][HLDS_STRIDE]
  float* smem = (float*)(lds_raw + 16 * HLDS_STRIDE * 2);  // 4160 floats

  int t = t_lstm;
  int wgid = dir * 5 + w;
  int gate = wv >> 2, q = wv & 3;
  const float* z = zbase + (size_t)(t & 1) * M_ * N2_;

  // persistent Whh B-fragments: wave covers cols n = gate*300 + w*64 + q*16 + (lane&15)
  short8 bfr[10];
  {
    int col = lane & 15;
    int u = w * 64 + q * 16 + col;
    int krow = (lane >> 4) * 8;
    if (u < H_) {
      const u16* base = whh + (size_t)(dir * G4_ + gate * H_ + u) * 320 + krow;
#pragma unroll
      for (int kk = 0; kk < 10; ++kk) bfr[kk] = *(const short8*)(base + kk * 32);
    } else {
#pragma unroll
      for (int kk = 0; kk < 10; ++kk) bfr[kk] = (short8){0, 0, 0, 0, 0, 0, 0, 0};
    }
  }

  // thread view for gate/classifier phase
  int b = tid >> 6;
  int u_loc = tid & 63;
  int u_glob = w * 64 + u_loc;
  bool active = u_glob < H_;
  float bias_r[4];
#pragma unroll
  for (int g = 0; g < 4; ++g)
    bias_r[g] = active ? bias[dir * G4_ + g * H_ + u_glob] : 0.f;

  float c_state = t > 0 ? cst[wgid * 1024 + tid] : 0.f;
  float clsacc[4] = {0.f, 0.f, 0.f, 0.f};

  for (int i = tid; i < 16 * HLDS_STRIDE; i += 1024) h_lds[i] = 0;
  __syncthreads();

  u32* hx_base = hxw + dir * 2 * HXW_SLOT;

  // poll set (balanced, max 5 words/thread):
  //   bits 0..3: dwordx4 at words [tid*4, tid*4+4)            (covers 0..4095)
  //   bit  4   : dword at word 4096 + (tid-256) for tid>=256  (covers 4096..4863)
  //              (tid<256 issues a harmless extra dword, pend bit stays 0 —
  //               keeps per-wave vmcnt counts uniform)
  // word layout i = b*304 + u; tagged (g+1)<<16 | bf16(h).
  // pend0: steady state (skip own slice). pendA: launch boundary (include own).
  int wB = 4096 + ((tid >= 256) ? (tid - 256) : tid);
  u32 pend0 = 0, pendA = 0;
  int lofs[5];
#pragma unroll
  for (int k = 0; k < 5; ++k) {
    int i = (k < 4) ? (tid * 4 + k) : wB;
    bool mine = (k < 4) || (tid >= 256);
    lofs[k] = 0;
    if (mine && i < 16 * 304) {
      int bb = i / 304;
      int uu = i - bb * 304;
      if (uu < H_) {
        lofs[k] = bb * HLDS_STRIDE + uu;
        pendA |= 1u << k;
        if (!(uu >= w * 64 && uu < (w + 1) * 64)) pend0 |= 1u << k;
      }
    }
  }

  for (int s_mod = 0; s_mod < S_; ++s_mod) {
    int g = t * S_ + s_mod;
    int s_in = dir ? (S_ - 1 - s_mod) : s_mod;

    // prefetch (independent of sync): z input row + Wcls column
    float z_in[4] = {0.f, 0.f, 0.f, 0.f}, wc[4] = {0.f, 0.f, 0.f, 0.f};
    if (active) {
      const float* zr = z + (size_t)(s_in * B_ + b) * N2_ + dir * G4_;
      int ycol = s_in * 600 + dir * H_ + u_glob;
#pragma unroll
      for (int gg = 0; gg < 4; ++gg) z_in[gg] = zr[gg * H_ + u_glob];
#pragma unroll
      for (int n = 0; n < 4; ++n) wc[n] = wcls[(size_t)n * (S_ * 600) + ycol];
    }

    if (g > 0) {
      const u32* src = hx_base + (g & 1) * HXW_SLOT;
      const u32* aA = src + tid * 4;
      const u32* aB = src + wB;
      u32 pend = (s_mod == 0) ? pendA : pend0;
      if (pend) {
        // pipelined agent-scope polling: 2 rounds in flight, counted vmcnt.
        // Round = {dwordx4, dword} (2 VMEM ops). vmcnt(2) waits for the OLDER
        // round (and, on entry, drains the z/wcls prefetch too). Results are
        // data-tied through "+v" so reads can't be hoisted past the wait.
        u32x4 rA, sA;
        u32 rB, sB;
        int tries = 0;
        asm volatile("global_load_dwordx4 %0, %2, off sc1\n\t"
                     "global_load_dword %1, %3, off sc1"
                     : "=&v"(rA), "=&v"(rB) : "v"(aA), "v"(aB) : "memory");
        for (;;) {
          asm volatile("global_load_dwordx4 %0, %2, off sc1\n\t"
                       "global_load_dword %1, %3, off sc1"
                       : "=&v"(sA), "=&v"(sB) : "v"(aA), "v"(aB) : "memory");
          asm volatile("s_waitcnt vmcnt(2)" : "+v"(rA), "+v"(rB) :: "memory");
          {
            u32 wd[5] = {rA[0], rA[1], rA[2], rA[3], rB};
#pragma unroll
            for (int k = 0; k < 5; ++k)
              if ((pend & (1u << k)) && (wd[k] >> 16) >= (u32)g) {
                h_lds[lofs[k]] = (u16)(wd[k] & 0xffffu);
                pend &= ~(1u << k);
              }
          }
          if (!pend || ++tries >= (1 << 20)) break;
          asm volatile("global_load_dwordx4 %0, %2, off sc1\n\t"
                       "global_load_dword %1, %3, off sc1"
                       : "=&v"(rA), "=&v"(rB) : "v"(aA), "v"(aB) : "memory");
          asm volatile("s_waitcnt vmcnt(2)" : "+v"(sA), "+v"(sB) :: "memory");
          {
            u32 wd[5] = {sA[0], sA[1], sA[2], sA[3], sB};
#pragma unroll
            for (int k = 0; k < 5; ++k)
              if ((pend & (1u << k)) && (wd[k] >> 16) >= (u32)g) {
                h_lds[lofs[k]] = (u16)(wd[k] & 0xffffu);
                pend &= ~(1u << k);
              }
          }
          if (!pend || ++tries >= (1 << 20)) break;
        }
        // drain the still-in-flight round before its dest regs get reused
        asm volatile("s_waitcnt vmcnt(0)" ::: "memory");
      }
      __syncthreads();
    }

    // recurrent GEMV tile via MFMA: D[b][u] = sum_k h[b,k] * Whh[n,k]
    {
      float4v acc = (float4v){0.f, 0.f, 0.f, 0.f};
      int m = lane & 15;
      int kbase = (lane >> 4) * 8;
      const u16* hl = h_lds + m * HLDS_STRIDE + kbase;
#pragma unroll
      for (int kk = 0; kk < 10; ++kk) {
        short8 af = *(const short8*)(hl + kk * 32);
        acc = __builtin_amdgcn_mfma_f32_16x16x32_bf16(af, bfr[kk], acc, 0, 0, 0);
      }
      int col = lane & 15;
      int rb = (lane >> 4) * 4;
#pragma unroll
      for (int r = 0; r < 4; r++)
        smem[(gate * 16 + rb + r) * 65 + q * 16 + col] = acc[r];
    }
    __syncthreads();

    if (active) {
      float zi = smem[(0 * 16 + b) * 65 + u_loc] + z_in[0] + bias_r[0];
      float zf = smem[(1 * 16 + b) * 65 + u_loc] + z_in[1] + bias_r[1];
      float zg = smem[(2 * 16 + b) * 65 + u_loc] + z_in[2] + bias_r[2];
      float zo = smem[(3 * 16 + b) * 65 + u_loc] + z_in[3] + bias_r[3];
      float ig = sigmoid_f(zi);
      float fg = sigmoid_f(zf);
      float gg = tanh_f(zg);
      float og = sigmoid_f(zo);
      c_state = fg * c_state + ig * gg;
      float hval = og * tanh_f(c_state);
      u16 hb = f2bf(hval);
      // publish ASAP: tagged word, relaxed agent scope (proven R1 semantics);
      // lane = u -> 64 contiguous words per wave = 4 cache lines
      u32 wrd = ((u32)(g + 1) << 16) | (u32)hb;
      __hip_atomic_store(&hx_base[((g + 1) & 1) * HXW_SLOT + b * 304 + u_glob], wrd,
                         __ATOMIC_RELAXED, __HIP_MEMORY_SCOPE_AGENT);
      // own slice goes straight to LDS for the next step
      h_lds[b * HLDS_STRIDE + u_glob] = hb;
      float rv = hval > 0.f ? hval : 0.f;
#pragma unroll
      for (int n = 0; n < 4; ++n) clsacc[n] += rv * wc[n];
    }

    if (s_mod == S_ - 1) {
      __syncthreads();
#pragma unroll
      for (int n = 0; n < 4; ++n) smem[(b * 64 + u_loc) * 4 + n] = clsacc[n];
      __syncthreads();
      if (tid < B_ * NC_) {
        int bb = tid >> 2, n = tid & 3;
        float s = 0.f;
        for (int u = 0; u < 64; ++u) s += smem[(bb * 64 + u) * 4 + n];
        atomicAdd(&outp[(t * B_ + bb) * NC_ + n], s);
      }
    }
  }
  cst[wgid * 1024 + tid] = c_state;
}

// ---------------------------------------------------------------------------
extern "C" void kernel_launch(void* const* d_in, const int* in_sizes, int n_in,
                              void* d_out, int out_size, void* d_ws, size_t ws_size,
                              hipStream_t stream) {
  const float* seq = (const float*)d_in[1];
  const float* sp = (const float*)d_in[2];
  const float* ep = (const float*)d_in[3];
  const float* cp = (const float*)d_in[4];
  const float* bsp = (const float*)d_in[5];
  const float* bep = (const float*)d_in[6];
  const float* bcp = (const float*)d_in[7];
  const float* um = (const float*)d_in[8];
  const float* nm = (const float*)d_in[9];
  const float* am = (const float*)d_in[10];
  const float* wihf = (const float*)d_in[11];
  const float* whhf = (const float*)d_in[12];
  const float* bihf = (const float*)d_in[13];
  const float* bhhf = (const float*)d_in[14];
  const float* wihb = (const float*)d_in[15];
  const float* whhb = (const float*)d_in[16];
  const float* bihb = (const float*)d_in[17];
  const float* bhhb = (const float*)d_in[18];
  const float* wcls = (const float*)d_in[19];
  const float* bcls = (const float*)d_in[20];

  char* ws = (char*)d_ws;
  size_t off = 0;
  auto alloc = [&](size_t bytes) -> char* {
    char* p = ws + off;
    off += (bytes + 255) & ~(size_t)255;
    return p;
  };
  u16* S0 = (u16*)alloc((size_t)T_ * M_ * D_ * 2);
  u16* SA = (u16*)alloc((size_t)T_ * M_ * D_ * 2);
  u16* SB = (u16*)alloc((size_t)T_ * M_ * D_ * 2);
  u16* SA0 = (u16*)alloc((size_t)M_ * D_ * 2);
  u16* SB0 = (u16*)alloc((size_t)M_ * D_ * 2);
  u16* WCAT = (u16*)alloc((size_t)N2_ * K5_ * 2);
  u16* WHH = (u16*)alloc((size_t)2 * G4_ * 320 * 2);
  float* BIAS = (float*)alloc((size_t)2 * G4_ * 4);
  float* Z = (float*)alloc((size_t)2 * M_ * N2_ * 4);   // parity double-buffer
  u32* HXW = (u32*)alloc((size_t)2 * 2 * HXW_SLOT * 4); // tagged h, 2 dirs x 2 slots
  float* CST = (float*)alloc((size_t)10 * 1024 * 4);

  if (off > ws_size) {
    fprintf(stderr, "[kernel] ws too small: need %zu, have %zu\n", off, ws_size);
    return;
  }

  hipLaunchKernelGGL(k_prep_s, dim3(T_ * M_ + M_), dim3(256), 0, stream,
                     seq, sp, ep, cp, bsp, bep, bcp, um, nm, am, S0, SA, SB, SA0, SB0);
  hipLaunchKernelGGL(k_prep_w, dim3(N2_ + 2 * G4_ + 1), dim3(256), 0, stream,
                     wihf, wihb, whhf, whhb, bihf, bhhf, bihb, bhhb, bcls,
                     WCAT, WHH, BIAS, (float*)d_out, HXW);
  // prologue: t=0 GEMM alone (fills Z slot 0), full-machine spread
  hipLaunchKernelGGL(k_main, dim3(NTILE), dim3(1024), 0, stream,
                     S0, SA, SB, SA0, SB0, WCAT, Z, WHH, BIAS, wcls, HXW,
                     (float*)d_out, CST, 0, 0, 0);
  for (int t = 0; t < T_; ++t) {
    // LSTM(t) on XCD0/1 + GEMM(t+1) on XCDs 2..7 hidden underneath
    hipLaunchKernelGGL(k_main, dim3(176), dim3(1024), 0, stream,
                       S0, SA, SB, SA0, SB0, WCAT, Z, WHH, BIAS, wcls, HXW,
                       (float*)d_out, CST, t, (t < T_ - 1) ? t + 1 : -1, 1);
  }
}

// Round 6
// 6095.779 us; speedup vs baseline: 1.2427x; 1.0274x over previous
//
#include <hip/hip_runtime.h>
#include <stdint.h>
#include <stdio.h>

#define T_ 10
#define B_ 16
#define S_ 200
#define D_ 768
#define H_ 300
#define NC_ 4
#define M_ (S_ * B_)   /* 3200 rows per t */
#define K5_ (5 * D_)   /* 3840 */
#define N2_ 2400       /* 2 dirs * 4H */
#define G4_ 1200       /* 4H */
#define HXW_SLOT 2432  /* u32 words per parity slot: 16 b x 152 (150 used, packed bf16 pairs) */
#define HLDS_STRIDE 344 /* u16; 172 u32 per b row */
#define NTILE 130       /* 13 x 10 grid of 256x256 GEMM tiles */

typedef unsigned short u16;
typedef unsigned int u32;
typedef __attribute__((ext_vector_type(8))) short short8;
typedef __attribute__((ext_vector_type(4))) float float4v;
typedef __attribute__((ext_vector_type(4))) unsigned int u32x4;

static __device__ __forceinline__ u16 f2bf(float x) {
  union { float f; u32 u; } v; v.f = x;
  u32 u = v.u;
  u32 r = (u + 0x7FFFu + ((u >> 16) & 1u)) >> 16;
  return (u16)r;
}

static __device__ __forceinline__ void async16(const void* g, void* l) {
  __builtin_amdgcn_global_load_lds((const __attribute__((address_space(1))) u32*)g,
                                   (__attribute__((address_space(3))) u32*)l, 16, 0, 0);
}

static __device__ __forceinline__ float sigmoid_f(float x) {
  return 1.f / (1.f + __expf(-x));
}
static __device__ __forceinline__ float tanh_f(float x) {
  float e = __expf(2.f * x);
  return 1.f - 2.f / (e + 1.f);   // safe at e=inf -> 1, e=0 -> -1
}

// ---------------------------------------------------------------------------
// K0a: build S0 = bf16(seq), SA = a .* seq, SB = b .* seq  (layout [t][s][b][768])
//      plus before-state SA0/SB0 (t=0 before-state weights on seq[0])
// ---------------------------------------------------------------------------
__global__ void k_prep_s(const float* __restrict__ seq,
                         const float* __restrict__ sp, const float* __restrict__ ep,
                         const float* __restrict__ cp,
                         const float* __restrict__ bsp, const float* __restrict__ bep,
                         const float* __restrict__ bcp,
                         const float* __restrict__ um, const float* __restrict__ nm,
                         const float* __restrict__ am,
                         u16* __restrict__ s0, u16* __restrict__ sa, u16* __restrict__ sb,
                         u16* __restrict__ sa0, u16* __restrict__ sb0) {
  int bid = blockIdx.x;
  int tid = threadIdx.x;  // 256
  if (bid < T_ * M_) {
    int t = bid / M_;
    int r = bid % M_;
    int s = r >> 4, b = r & 15;
    float c0 = cp[(t * B_ + b) * NC_ + 0];
    float c1 = cp[(t * B_ + b) * NC_ + 1];
    float c2 = cp[(t * B_ + b) * NC_ + 2];
    int mi = (b * T_ + t) * S_ + s;
    float w = am[mi] * c0 + um[mi] * c1 + nm[mi] * c2;
    float aw = sp[(t * B_ + b) * S_ + s] * w;
    float bw = ep[(t * B_ + b) * S_ + s] * w;
    const float* x = seq + ((size_t)(t * B_ + b) * S_ + s) * D_;
    size_t ob = (size_t)bid * D_;
    for (int d = tid; d < D_; d += 256) {
      float xv = x[d];
      s0[ob + d] = f2bf(xv);
      sa[ob + d] = f2bf(aw * xv);
      sb[ob + d] = f2bf(bw * xv);
    }
  } else {
    int r = bid - T_ * M_;
    int s = r >> 4, b = r & 15;
    float c0 = bcp[b * NC_ + 0], c1 = bcp[b * NC_ + 1], c2 = bcp[b * NC_ + 2];
    int mi = (b * T_ + 0) * S_ + s;
    float w = am[mi] * c0 + um[mi] * c1 + nm[mi] * c2;
    float aw = bsp[b * S_ + s] * w;
    float bw = bep[b * S_ + s] * w;
    const float* x = seq + ((size_t)b * S_ + s) * D_;
    size_t ob = (size_t)r * D_;
    for (int d = tid; d < D_; d += 256) {
      float xv = x[d];
      sa0[ob + d] = f2bf(aw * xv);
      sb0[ob + d] = f2bf(bw * xv);
    }
  }
}

// ---------------------------------------------------------------------------
// K0b: Wcat bf16 [2400][3840], Whh padded bf16 [2][1200][320], bias=bih+bhh,
//      d_out seeded with bcls, hxw payload + tagb (per-WG step tags) zeroed
// ---------------------------------------------------------------------------
__global__ void k_prep_w(const float* __restrict__ wf, const float* __restrict__ wb,
                         const float* __restrict__ whf, const float* __restrict__ whb,
                         const float* __restrict__ bihf, const float* __restrict__ bhhf,
                         const float* __restrict__ bihb, const float* __restrict__ bhhb,
                         const float* __restrict__ bcls,
                         u16* __restrict__ wcat, u16* __restrict__ whh,
                         float* __restrict__ bias, float* __restrict__ outp,
                         u32* __restrict__ hxw, u32* __restrict__ tagb) {
  int bid = blockIdx.x, tid = threadIdx.x;
  if (bid < N2_) {
    const float* src = bid < G4_ ? wf + (size_t)bid * K5_ : wb + (size_t)(bid - G4_) * K5_;
    u16* dst = wcat + (size_t)bid * K5_;
    for (int k = tid; k < K5_; k += 256) dst[k] = f2bf(src[k]);
  } else if (bid < N2_ + 2 * G4_) {
    int r = bid - N2_;
    int dir = r / G4_, n = r % G4_;
    const float* src = (dir ? whb : whf) + (size_t)n * H_;
    u16* dst = whh + (size_t)(dir * G4_ + n) * 320;
    for (int k = tid; k < 320; k += 256) dst[k] = (k < H_) ? f2bf(src[k]) : (u16)0;
  } else {
    for (int i = tid; i < 2 * G4_; i += 256) {
      int dir = i / G4_, n = i % G4_;
      bias[i] = dir ? (bihb[n] + bhhb[n]) : (bihf[n] + bhhf[n]);
    }
    for (int i = tid; i < T_ * B_ * NC_; i += 256) outp[i] = bcls[i & 3];
    for (int i = tid; i < 2 * 2 * HXW_SLOT; i += 256) hxw[i] = 0;
    if (tid < 32) tagb[tid] = 0;  // tag 0 = nothing published
  }
}

// ---------------------------------------------------------------------------
// K_MAIN: fused launch per t, XCD-aware role map (blockIdx%8 round-robins
// over the 8 XCDs; if that mapping ever changes, only SPEED is affected —
// all exchange traffic is agent-scope/MALL, placement-independent).
//   steady==1 (grid 176):
//     bid%8==0, bid/8<5  -> LSTM dir0 wg w=bid/8
//     bid%8==1, bid/8<5  -> LSTM dir1 wg w=bid/8
//     bid%8>=2           -> GEMM worker, tile = (bid/8)*6 + bid%8-2
//   steady==0 (grid 130): pure GEMM prologue, tile = bid.
//
// h-exchange (one-tag-per-WG protocol):
//   payload: packed bf16 pairs, word i = b*152 + u/2, parity slot (g+1)&1,
//            stored relaxed-agent (contiguous per wave -> few lines).
//   publish: data stores -> __syncthreads() (compiler drains vmcnt(0), so
//            data has reached the MALL) -> tid0 stores tag g+1 (one word).
//   consume: spin on the 5-tag line only (1 line/round, sc1); when all >= g,
//            the tag's MALL arrival postdates all data MALL arrivals, and our
//            bulk sc1 reads are issued after the tag loads RETURNED -> they
//            observe the published data. One dwordx4/thread covers the slot.
//   slot overwrite safety: tag g+2 publish requires all WGs past step g+1,
//   which requires this WG's tag g+1, which follows its bulk read of slot g&1.
// ---------------------------------------------------------------------------
__global__ __launch_bounds__(1024) void k_main(
    const u16* __restrict__ s0, const u16* __restrict__ sa, const u16* __restrict__ sb,
    const u16* __restrict__ sa0, const u16* __restrict__ sb0,
    const u16* __restrict__ wcat, float* __restrict__ zbase,
    const u16* __restrict__ whh, const float* __restrict__ bias,
    const float* __restrict__ wcls, u32* __restrict__ hxw, u32* __restrict__ tagb,
    float* __restrict__ outp, float* __restrict__ cst,
    int t_lstm, int t_gemm, int steady) {
  __shared__ __align__(16) char lds_raw[32768];

  int tid = threadIdx.x;
  int lane = tid & 63, wv = tid >> 6;
  int bid = (int)blockIdx.x;

  int dir = 0, w = 0, tile = -1;
  bool lstm_role = false;
  if (steady) {
    int grp = bid >> 3, sub = bid & 7;
    if (sub < 2) {
      if (grp < 5) { lstm_role = true; dir = sub; w = grp; }
      else return;
    } else {
      if (t_gemm < 0) return;
      tile = grp * 6 + (sub - 2);
      if (tile >= NTILE) return;
    }
  } else {
    tile = bid;
  }

  if (!lstm_role) {
    // ---------------- GEMM path: one 256x256 tile ----------------
    int mt = tile % 13, nt = tile / 13;
    int m0 = mt * 256, n0 = nt * 256;
    u16* As = (u16*)lds_raw;             // [256][32]
    u16* Bs = (u16*)(lds_raw + 16384);   // [256][32]
    int wm = wv & 3, wn = wv >> 2;

    const u16* ap[5];
    ap[0] = s0 + (size_t)t_gemm * M_ * D_;
    ap[1] = sa + (size_t)t_gemm * M_ * D_;
    ap[2] = sb + (size_t)t_gemm * M_ * D_;
    ap[3] = t_gemm ? sa + (size_t)(t_gemm - 1) * M_ * D_ : sa0;
    ap[4] = t_gemm ? sb + (size_t)(t_gemm - 1) * M_ * D_ : sb0;
    float* z = zbase + (size_t)(t_gemm & 1) * M_ * N2_;

    float4v acc[4][4];
#pragma unroll
    for (int i = 0; i < 4; i++)
#pragma unroll
      for (int j = 0; j < 4; j++) acc[i][j] = (float4v){0.f, 0.f, 0.f, 0.f};

    int rowA = tid >> 2;   // 0..255
    int seg = tid & 3;
    int mr = m0 + rowA; if (mr > M_ - 1) mr = M_ - 1;
    int nr = n0 + rowA; if (nr > N2_ - 1) nr = N2_ - 1;

    for (int which = 0; which < 5; ++which) {
      const u16* ab = which == 0 ? ap[0] : which == 1 ? ap[1] : which == 2 ? ap[2]
                      : which == 3 ? ap[3] : ap[4];
      for (int kk = 0; kk < 24; ++kk) {
        int kof = kk * 32;
        async16(ab + (size_t)mr * D_ + kof + seg * 8, As + wv * 512);
        async16(wcat + (size_t)nr * K5_ + which * D_ + kof + seg * 8, Bs + wv * 512);
        __syncthreads();
        short8 af[4], bf[4];
#pragma unroll
        for (int i = 0; i < 4; i++) {
          af[i] = *(const short8*)&As[(wm * 64 + i * 16 + (lane & 15)) * 32 + (lane >> 4) * 8];
          bf[i] = *(const short8*)&Bs[(wn * 64 + i * 16 + (lane & 15)) * 32 + (lane >> 4) * 8];
        }
#pragma unroll
        for (int i = 0; i < 4; i++)
#pragma unroll
          for (int j = 0; j < 4; j++)
            acc[i][j] = __builtin_amdgcn_mfma_f32_16x16x32_bf16(af[i], bf[j], acc[i][j], 0, 0, 0);
        __syncthreads();
      }
    }
#pragma unroll
    for (int i = 0; i < 4; i++) {
      int m = m0 + wm * 64 + i * 16 + (lane >> 4) * 4;
#pragma unroll
      for (int j = 0; j < 4; j++) {
        int n = n0 + wn * 64 + j * 16 + (lane & 15);
        if (n < N2_) {
#pragma unroll
          for (int r = 0; r < 4; r++)
            if (m + r < M_) z[(size_t)(m + r) * N2_ + n] = acc[i][j][r];
        }
      }
    }
    return;
  }

  // ---------------- LSTM path ----------------
  u16* h_lds = (u16*)lds_raw;                              // [16][HLDS_STRIDE]
  u32* h32 = (u32*)lds_raw;                                // same, u32 view (172/b)
  float* smem = (float*)(lds_raw + 16 * HLDS_STRIDE * 2);  // 4160 floats

  int t = t_lstm;
  int wgid = dir * 5 + w;
  int gate = wv >> 2, q = wv & 3;
  const float* z = zbase + (size_t)(t & 1) * M_ * N2_;

  // persistent Whh B-fragments: wave covers cols n = gate*300 + w*64 + q*16 + (lane&15)
  short8 bfr[10];
  {
    int col = lane & 15;
    int u = w * 64 + q * 16 + col;
    int krow = (lane >> 4) * 8;
    if (u < H_) {
      const u16* base = whh + (size_t)(dir * G4_ + gate * H_ + u) * 320 + krow;
#pragma unroll
      for (int kk = 0; kk < 10; ++kk) bfr[kk] = *(const short8*)(base + kk * 32);
    } else {
#pragma unroll
      for (int kk = 0; kk < 10; ++kk) bfr[kk] = (short8){0, 0, 0, 0, 0, 0, 0, 0};
    }
  }

  // thread view for gate/classifier phase
  int b = tid >> 6;
  int u_loc = tid & 63;
  int u_glob = w * 64 + u_loc;
  bool active = u_glob < H_;
  float bias_r[4];
#pragma unroll
  for (int g = 0; g < 4; ++g)
    bias_r[g] = active ? bias[dir * G4_ + g * H_ + u_glob] : 0.f;

  float c_state = t > 0 ? cst[wgid * 1024 + tid] : 0.f;
  float clsacc[4] = {0.f, 0.f, 0.f, 0.f};

  for (int i = tid; i < 16 * HLDS_STRIDE; i += 1024) h_lds[i] = 0;
  __syncthreads();

  u32* hx_base = hxw + dir * 2 * HXW_SLOT;
  u32* tag_base = tagb + dir * 16;   // 5 tags in one cache line

  // bulk-read geometry: tid<608 read dwordx4 at word tid*4 (608*4 = 2432 = slot)
  // word i = b*152 + j holds h[2j], h[2j+1] (valid j<150)
  bool rd_on = tid < 608;
  int rdw = tid * 4;
  int rlofs[4];
  u32 rmask = 0;
#pragma unroll
  for (int k = 0; k < 4; ++k) {
    int i = rdw + k;
    rlofs[k] = 0;
    if (rd_on && i < 2432) {
      int bb = i / 152;
      int jj = i - bb * 152;
      if (jj < 150) { rlofs[k] = bb * 172 + jj; rmask |= 1u << k; }
    }
  }

  for (int s_mod = 0; s_mod < S_; ++s_mod) {
    int g = t * S_ + s_mod;
    int s_in = dir ? (S_ - 1 - s_mod) : s_mod;

    // prefetch (independent of sync): z input row + Wcls column
    float z_in[4] = {0.f, 0.f, 0.f, 0.f}, wc[4] = {0.f, 0.f, 0.f, 0.f};
    if (active) {
      const float* zr = z + (size_t)(s_in * B_ + b) * N2_ + dir * G4_;
      int ycol = s_in * 600 + dir * H_ + u_glob;
#pragma unroll
      for (int gg = 0; gg < 4; ++gg) z_in[gg] = zr[gg * H_ + u_glob];
#pragma unroll
      for (int n = 0; n < 4; ++n) wc[n] = wcls[(size_t)n * (S_ * 600) + ycol];
    }

    if (g > 0) {
      // 1) spin on the 5-tag line only
      const u32* tp0 = tag_base;
      const u32* tp4 = tag_base + 4;
      int tries = 0;
      for (;;) {
        u32x4 tA; u32 tB;
        asm volatile("global_load_dwordx4 %0, %2, off sc1\n\t"
                     "global_load_dword %1, %3, off sc1\n\t"
                     "s_waitcnt vmcnt(0)"
                     : "=&v"(tA), "=&v"(tB) : "v"(tp0), "v"(tp4) : "memory");
        if (tA[0] >= (u32)g && tA[1] >= (u32)g && tA[2] >= (u32)g &&
            tA[3] >= (u32)g && tB >= (u32)g) break;
        if (++tries >= (1 << 20)) break;
      }
      __builtin_amdgcn_sched_barrier(0);
      // 2) bulk payload read (issued only after tag loads returned)
      const u32* src = hx_base + (g & 1) * HXW_SLOT;
      if (rd_on) {
        u32x4 d;
        asm volatile("global_load_dwordx4 %0, %1, off sc1\n\t"
                     "s_waitcnt vmcnt(0)"
                     : "=&v"(d) : "v"(src + rdw) : "memory");
#pragma unroll
        for (int k = 0; k < 4; ++k)
          if (rmask & (1u << k)) h32[rlofs[k]] = d[k];
      }
      __syncthreads();
    }

    // recurrent GEMV tile via MFMA: D[b][u] = sum_k h[b,k] * Whh[n,k]
    {
      float4v acc = (float4v){0.f, 0.f, 0.f, 0.f};
      int m = lane & 15;
      int kbase = (lane >> 4) * 8;
      const u16* hl = h_lds + m * HLDS_STRIDE + kbase;
#pragma unroll
      for (int kk = 0; kk < 10; ++kk) {
        short8 af = *(const short8*)(hl + kk * 32);
        acc = __builtin_amdgcn_mfma_f32_16x16x32_bf16(af, bfr[kk], acc, 0, 0, 0);
      }
      int col = lane & 15;
      int rb = (lane >> 4) * 4;
#pragma unroll
      for (int r = 0; r < 4; r++)
        smem[(gate * 16 + rb + r) * 65 + q * 16 + col] = acc[r];
    }
    __syncthreads();

    // gates: computed by ALL threads (inactive cols have zero weights/inputs),
    // stores guarded by `active`
    {
      float zi = smem[(0 * 16 + b) * 65 + u_loc] + z_in[0] + bias_r[0];
      float zf = smem[(1 * 16 + b) * 65 + u_loc] + z_in[1] + bias_r[1];
      float zg = smem[(2 * 16 + b) * 65 + u_loc] + z_in[2] + bias_r[2];
      float zo = smem[(3 * 16 + b) * 65 + u_loc] + z_in[3] + bias_r[3];
      float ig = sigmoid_f(zi);
      float fg = sigmoid_f(zf);
      float gg = tanh_f(zg);
      float og = sigmoid_f(zo);
      c_state = fg * c_state + ig * gg;
      float hval = og * tanh_f(c_state);
      u16 hb = f2bf(hval);
      u32 mine = (u32)hb;
      u32 other = (u32)__shfl_xor((int)mine, 1);   // partner h (u^1) — uniform exec
      if (active) {
        h_lds[b * HLDS_STRIDE + u_glob] = hb;      // own value for next step
        float rv = hval > 0.f ? hval : 0.f;
#pragma unroll
        for (int n = 0; n < 4; ++n) clsacc[n] += rv * wc[n];
      }
      if (active && !(u_loc & 1)) {
        u32 wrd = mine | (other << 16);            // h[u] lo, h[u+1] hi
        __hip_atomic_store(&hx_base[((g + 1) & 1) * HXW_SLOT + b * 152 + (u_glob >> 1)],
                           wrd, __ATOMIC_RELAXED, __HIP_MEMORY_SCOPE_AGENT);
      }
    }
    // drain (syncthreads emits s_waitcnt vmcnt(0) before s_barrier), then tag
    __syncthreads();
    if (tid == 0)
      __hip_atomic_store(&tag_base[w], (u32)(g + 1),
                         __ATOMIC_RELAXED, __HIP_MEMORY_SCOPE_AGENT);

    if (s_mod == S_ - 1) {
      __syncthreads();
#pragma unroll
      for (int n = 0; n < 4; ++n) smem[(b * 64 + u_loc) * 4 + n] = clsacc[n];
      __syncthreads();
      if (tid < B_ * NC_) {
        int bb = tid >> 2, n = tid & 3;
        float s = 0.f;
        for (int u = 0; u < 64; ++u) s += smem[(bb * 64 + u) * 4 + n];
        atomicAdd(&outp[(t * B_ + bb) * NC_ + n], s);
      }
    }
  }
  cst[wgid * 1024 + tid] = c_state;
}

// ---------------------------------------------------------------------------
extern "C" void kernel_launch(void* const* d_in, const int* in_sizes, int n_in,
                              void* d_out, int out_size, void* d_ws, size_t ws_size,
                              hipStream_t stream) {
  const float* seq = (const float*)d_in[1];
  const float* sp = (const float*)d_in[2];
  const float* ep = (const float*)d_in[3];
  const float* cp = (const float*)d_in[4];
  const float* bsp = (const float*)d_in[5];
  const float* bep = (const float*)d_in[6];
  const float* bcp = (const float*)d_in[7];
  const float* um = (const float*)d_in[8];
  const float* nm = (const float*)d_in[9];
  const float* am = (const float*)d_in[10];
  const float* wihf = (const float*)d_in[11];
  const float* whhf = (const float*)d_in[12];
  const float* bihf = (const float*)d_in[13];
  const float* bhhf = (const float*)d_in[14];
  const float* wihb = (const float*)d_in[15];
  const float* whhb = (const float*)d_in[16];
  const float* bihb = (const float*)d_in[17];
  const float* bhhb = (const float*)d_in[18];
  const float* wcls = (const float*)d_in[19];
  const float* bcls = (const float*)d_in[20];

  char* ws = (char*)d_ws;
  size_t off = 0;
  auto alloc = [&](size_t bytes) -> char* {
    char* p = ws + off;
    off += (bytes + 255) & ~(size_t)255;
    return p;
  };
  u16* S0 = (u16*)alloc((size_t)T_ * M_ * D_ * 2);
  u16* SA = (u16*)alloc((size_t)T_ * M_ * D_ * 2);
  u16* SB = (u16*)alloc((size_t)T_ * M_ * D_ * 2);
  u16* SA0 = (u16*)alloc((size_t)M_ * D_ * 2);
  u16* SB0 = (u16*)alloc((size_t)M_ * D_ * 2);
  u16* WCAT = (u16*)alloc((size_t)N2_ * K5_ * 2);
  u16* WHH = (u16*)alloc((size_t)2 * G4_ * 320 * 2);
  float* BIAS = (float*)alloc((size_t)2 * G4_ * 4);
  float* Z = (float*)alloc((size_t)2 * M_ * N2_ * 4);   // parity double-buffer
  u32* HXW = (u32*)alloc((size_t)2 * 2 * HXW_SLOT * 4); // packed h, 2 dirs x 2 slots
  u32* TAGB = (u32*)alloc((size_t)32 * 4);              // per-WG step tags (1 line/dir)
  float* CST = (float*)alloc((size_t)10 * 1024 * 4);

  if (off > ws_size) {
    fprintf(stderr, "[kernel] ws too small: need %zu, have %zu\n", off, ws_size);
    return;
  }

  hipLaunchKernelGGL(k_prep_s, dim3(T_ * M_ + M_), dim3(256), 0, stream,
                     seq, sp, ep, cp, bsp, bep, bcp, um, nm, am, S0, SA, SB, SA0, SB0);
  hipLaunchKernelGGL(k_prep_w, dim3(N2_ + 2 * G4_ + 1), dim3(256), 0, stream,
                     wihf, wihb, whhf, whhb, bihf, bhhf, bihb, bhhb, bcls,
                     WCAT, WHH, BIAS, (float*)d_out, HXW, TAGB);
  // prologue: t=0 GEMM alone (fills Z slot 0), full-machine spread
  hipLaunchKernelGGL(k_main, dim3(NTILE), dim3(1024), 0, stream,
                     S0, SA, SB, SA0, SB0, WCAT, Z, WHH, BIAS, wcls, HXW, TAGB,
                     (float*)d_out, CST, 0, 0, 0);
  for (int t = 0; t < T_; ++t) {
    // LSTM(t) on XCD0/1 + GEMM(t+1) on XCDs 2..7 hidden underneath
    hipLaunchKernelGGL(k_main, dim3(176), dim3(1024), 0, stream,
                       S0, SA, SB, SA0, SB0, WCAT, Z, WHH, BIAS, wcls, HXW, TAGB,
                       (float*)d_out, CST, t, (t < T_ - 1) ? t + 1 : -1, 1);
  }
}